// Round 10
// baseline (543.256 us; speedup 1.0000x reference)
//
#include <hip/hip_runtime.h>
#include <cstddef>

// Problem constants
#define B_ 128
#define H_ 1024
#define S_ 512

// ======================================================================
// GEMM: M=128 (all batch), BN=16, KC=64/chunk, 256 thr = 4 waves.
// Intra-block K-split: wave w handles k in [w*16, w*16+16) of each chunk,
// accumulating its own split-K plane (plane = blockIdx.y*4 + w). A combine
// kernel (or consumer) sums the 16 planes. Per k-step each thread does
// 3 ds_read_b128 for 32 FMAs. A transposed in LDS: As[k][bpad(b)],
// bpad(b)=b+((b>>4)<<2), ld=156 -> 2-phase minimum conflict level.
// W as Wt[k][n], ld=20: contiguous + broadcast = 1 phase.
// ======================================================================

__device__ __forceinline__ int bpad(int b){ return b + ((b >> 4) << 2); }

#define LDA 156
#define LDW 20

__device__ __forceinline__ void stage_A2(float* As, const float* __restrict__ A, int k0, int tid){
  int c4 = tid & 15, rowg = tid >> 4;
#pragma unroll
  for (int p = 0; p < 8; ++p){
    int row = p*16 + rowg;
    const float4 v = *reinterpret_cast<const float4*>(A + (size_t)row*H_ + k0 + c4*4);
    float* d = As + (c4*4)*LDA + bpad(row);
    d[0]     = v.x;
    d[LDA]   = v.y;
    d[2*LDA] = v.z;
    d[3*LDA] = v.w;
  }
}

// W row-major [N][ldw] (weight rows = output features, contiguous K)
__device__ __forceinline__ void stage_Wt_wt(float* Wt, const float* __restrict__ W, int n0, int k0, int ldw, int tid){
  int n = tid >> 4, c4 = tid & 15;
  const float4 v = *reinterpret_cast<const float4*>(W + (size_t)(n0+n)*ldw + k0 + c4*4);
  float* d = Wt + (c4*4)*LDW + n;
  d[0]     = v.x;
  d[LDW]   = v.y;
  d[2*LDW] = v.z;
  d[3*LDW] = v.w;
}

// W k-major [K][ldw] (q = rnn @ W_attn case): Wt[k][n] = W[k0+k][n0+n]
__device__ __forceinline__ void stage_Wt_wn(float* Wt, const float* __restrict__ W, int n0, int k0, int ldw, int tid){
  int k = tid >> 2, c4 = tid & 3;
  const float4 v = *reinterpret_cast<const float4*>(W + (size_t)(k0+k)*ldw + n0 + c4*4);
  *reinterpret_cast<float4*>(Wt + k*LDW + c4*4) = v;
}

__device__ __forceinline__ void compute_chunk2(const float* As, const float* Wt, int wave, int bp0, int ng,
                                               float acc[8][4]){
#pragma unroll
  for (int kk = 0; kk < 16; ++kk){
    int k = wave*16 + kk;
    const float* r = As + k*LDA;
    float a[8], w[4];
    *reinterpret_cast<float4*>(&a[0]) = *reinterpret_cast<const float4*>(r + bp0);
    *reinterpret_cast<float4*>(&a[4]) = *reinterpret_cast<const float4*>(r + bp0 + 4);
    *reinterpret_cast<float4*>(&w[0]) = *reinterpret_cast<const float4*>(Wt + k*LDW + ng*4);
#pragma unroll
    for (int i = 0; i < 8; ++i)
#pragma unroll
      for (int j = 0; j < 4; ++j)
        acc[i][j] = fmaf(a[i], w[j], acc[i][j]);
  }
}

// ---------------- K1: gi|gh GEMM partials -> G[8][128][6144] ----------
__global__ __launch_bounds__(256) void gru_gemm(const float* __restrict__ Ain, const float* __restrict__ Ah,
                                                const float* __restrict__ Wih, const float* __restrict__ Whh,
                                                float* __restrict__ G){
  __shared__ float As[64*LDA];
  __shared__ float Wt[64*LDW];
  int tid = threadIdx.x;
  int n0g = blockIdx.x * 16;
  int kbase = blockIdx.y * 512;
  const float* A; const float* W; int n0;
  if (n0g < 3072){ A = Ain; W = Wih; n0 = n0g; }
  else           { A = Ah;  W = Whh; n0 = n0g - 3072; }
  int wave = tid >> 6, lane = tid & 63;
  int bg = lane & 15, ng = lane >> 4;
  int b0 = bg*8, bp0 = bpad(b0);
  float acc[8][4] = {};
  for (int kq = 0; kq < 512; kq += 64){
    int k0 = kbase + kq;
    __syncthreads();
    stage_A2(As, A, k0, tid);
    stage_Wt_wt(Wt, W, n0, k0, H_, tid);
    __syncthreads();
    compute_chunk2(As, Wt, wave, bp0, ng, acc);
  }
  float* Gp = G + (size_t)(blockIdx.y*4 + wave) * 786432;
#pragma unroll
  for (int i = 0; i < 8; ++i){
    float4 v = make_float4(acc[i][0], acc[i][1], acc[i][2], acc[i][3]);
    *reinterpret_cast<float4*>(Gp + (size_t)(b0+i)*6144 + n0g + ng*4) = v;
  }
}

// ---------------- generic split-K partial GEMM (K3 q, K7 concat, K8 out)
template<int KSUB, bool WT, bool ASPLIT>
__global__ __launch_bounds__(256) void gemm_partial(const float* __restrict__ A1, const float* __restrict__ A2,
                                                    const float* __restrict__ W, int ldw,
                                                    float* __restrict__ partial){
  __shared__ float As[64*LDA];
  __shared__ float Wt[64*LDW];
  int tid = threadIdx.x;
  int n0 = blockIdx.x * 16;
  int kbase = blockIdx.y * KSUB;
  int wave = tid >> 6, lane = tid & 63;
  int bg = lane & 15, ng = lane >> 4;
  int b0 = bg*8, bp0 = bpad(b0);
  float acc[8][4] = {};
  for (int kq = 0; kq < KSUB; kq += 64){
    int k0 = kbase + kq;
    const float* A = A1; int keff = k0;
    if (ASPLIT && k0 >= 1024){ A = A2; keff = k0 - 1024; }
    __syncthreads();
    stage_A2(As, A, keff, tid);
    if (WT) stage_Wt_wt(Wt, W, n0, k0, ldw, tid);
    else    stage_Wt_wn(Wt, W, n0, k0, ldw, tid);
    __syncthreads();
    compute_chunk2(As, Wt, wave, bp0, ng, acc);
  }
  float* P = partial + (size_t)(blockIdx.y*4 + wave) * (B_*H_);
#pragma unroll
  for (int i = 0; i < 8; ++i){
    float4 v = make_float4(acc[i][0], acc[i][1], acc[i][2], acc[i][3]);
    *reinterpret_cast<float4*>(P + (size_t)(b0+i)*1024 + n0 + ng*4) = v;
  }
}

// ---------------- combine: sum 16 partial planes + bias + activation --
template<int ACT>
__global__ __launch_bounds__(256) void combine(const float* __restrict__ partial, const float* __restrict__ bias,
                                               float* __restrict__ C){
  int idx = blockIdx.x*256 + threadIdx.x;   // 0..131071
  float v = 0.f;
#pragma unroll
  for (int j = 0; j < 16; ++j) v += partial[(size_t)j*(B_*H_) + idx];
  if (bias) v += bias[idx & 1023];
  if (ACT == 1) v = tanhf(v);
  if (ACT == 2) v = 1.f/(1.f + expf(-v));
  C[idx] = v;
}

// ---------------- K2: GRU gates (sums 8 K1 planes + biases) -> rnn, t[b]
__global__ __launch_bounds__(1024) void gru_gates(const float* __restrict__ G, const float* __restrict__ h,
                                                  const float* __restrict__ bih, const float* __restrict__ bhh,
                                                  const float* __restrict__ ba,
                                                  float* __restrict__ rnn, float* __restrict__ hid_out,
                                                  float* __restrict__ t){
  int b = blockIdx.x, c = threadIdx.x;
  __shared__ float red[16];
  float ir = bih[c], iz = bih[c+1024], in_ = bih[c+2048];
  float hr = bhh[c], hz = bhh[c+1024], hn  = bhh[c+2048];
#pragma unroll
  for (int p = 0; p < 8; ++p){
    const float* g = G + (size_t)p*786432 + (size_t)b*6144;
    ir  += g[c];      iz += g[c+1024]; in_ += g[c+2048];
    hr  += g[c+3072]; hz += g[c+4096]; hn  += g[c+5120];
  }
  float r = 1.f/(1.f + expf(-(ir + hr)));
  float z = 1.f/(1.f + expf(-(iz + hz)));
  float n = tanhf(in_ + r*hn);
  float hv = h[(size_t)b*H_ + c];
  float o = (1.f - z)*n + z*hv;
  rnn[(size_t)b*H_ + c] = o;
  hid_out[(size_t)b*H_ + c] = o;
  // block-reduce o * b_attn[c] -> t[b]
  float s = o * ba[c];
#pragma unroll
  for (int off = 1; off < 64; off <<= 1) s += __shfl_xor(s, off, 64);
  if ((c & 63) == 0) red[c >> 6] = s;
  __syncthreads();
  if (c == 0){
    float acc = 0.f;
#pragma unroll
    for (int j = 0; j < 16; ++j) acc += red[j];
    t[b] = acc;
  }
}

// ---------------- K4: one-pass flash attention over enc ---------------
// grid (128 b, 8 chunk) x 256 thr (4 waves). Wave owns 16 s-rows of one b.
// q read dense (combined by combine<0> node — inline 16-plane sum was a
// 256 MB L2-traffic regression in R9).
__global__ __launch_bounds__(256) void attn_pass(const float* __restrict__ enc, const float* __restrict__ q,
                                                 const float* __restrict__ t, float* __restrict__ e_out,
                                                 float* __restrict__ ctxp, float* __restrict__ mw){
  int b = blockIdx.x;
  int chunk = blockIdx.y;
  int wave = threadIdx.x >> 6;
  int lane = threadIdx.x & 63;
  int s0 = chunk*64 + wave*16;

  float qv[4][4];
#pragma unroll
  for (int k = 0; k < 4; ++k)
    *reinterpret_cast<float4*>(qv[k]) = *reinterpret_cast<const float4*>(q + (size_t)b*H_ + k*256 + lane*4);
  const float tb = t[b];

  float m = -INFINITY;
  float ctx[4][4] = {{0}};
  const float* rowp = enc + ((size_t)s0 * B_ + b) * H_;
  float rv[4][4];
#pragma unroll
  for (int k = 0; k < 4; ++k)
    *reinterpret_cast<float4*>(rv[k]) = *reinterpret_cast<const float4*>(rowp + k*256 + lane*4);

  for (int i = 0; i < 16; ++i){
    float nv[4][4];
    if (i < 15){
      const float* np = rowp + (size_t)B_*H_;
#pragma unroll
      for (int k = 0; k < 4; ++k)
        *reinterpret_cast<float4*>(nv[k]) = *reinterpret_cast<const float4*>(np + k*256 + lane*4);
    }
    float p = 0.f;
#pragma unroll
    for (int k = 0; k < 4; ++k)
#pragma unroll
      for (int j = 0; j < 4; ++j) p = fmaf(rv[k][j], qv[k][j], p);
#pragma unroll
    for (int off = 1; off < 64; off <<= 1) p += __shfl_xor(p, off, 64);
    float e = p + tb;
    if (lane == 0) e_out[(size_t)b*S_ + s0 + i] = e;
    float mn = fmaxf(m, e);
    float sc = expf(m - mn);     // 0 on first iter (m=-inf)
    float w  = expf(e - mn);
#pragma unroll
    for (int k = 0; k < 4; ++k)
#pragma unroll
      for (int j = 0; j < 4; ++j) ctx[k][j] = fmaf(w, rv[k][j], ctx[k][j]*sc);
    m = mn;
    rowp += (size_t)B_*H_;
    if (i < 15){
#pragma unroll
      for (int k = 0; k < 4; ++k)
#pragma unroll
        for (int j = 0; j < 4; ++j) rv[k][j] = nv[k][j];
    }
  }
  int pidx = b*32 + chunk*4 + wave;
  float* cp = ctxp + (size_t)pidx*H_;
#pragma unroll
  for (int k = 0; k < 4; ++k)
    *reinterpret_cast<float4*>(cp + k*256 + lane*4) = *reinterpret_cast<const float4*>(ctx[k]);
  if (lane == 0) mw[pidx] = m;
}

// ---------------- K5: softmax (attn_weights out) + ctx combine --------
__global__ __launch_bounds__(256) void softmax_combine(const float* __restrict__ e, const float* __restrict__ mw,
                                                       const float* __restrict__ ctxp, float* __restrict__ attn_out,
                                                       float* __restrict__ ctx){
  int b = blockIdx.x;
  int tid = threadIdx.x;
  __shared__ float red[4];
  __shared__ float Msh, Lsh;
  __shared__ float scs[32];
  float e0 = e[(size_t)b*S_ + tid];
  float e1 = e[(size_t)b*S_ + 256 + tid];
  float mx = fmaxf(e0, e1);
#pragma unroll
  for (int off = 1; off < 64; off <<= 1) mx = fmaxf(mx, __shfl_xor(mx, off, 64));
  if ((tid & 63) == 0) red[tid >> 6] = mx;
  __syncthreads();
  if (tid == 0) Msh = fmaxf(fmaxf(red[0], red[1]), fmaxf(red[2], red[3]));
  __syncthreads();
  float M = Msh;
  float w0 = expf(e0 - M), w1 = expf(e1 - M);
  float ls = w0 + w1;
#pragma unroll
  for (int off = 1; off < 64; off <<= 1) ls += __shfl_xor(ls, off, 64);
  if ((tid & 63) == 0) red[tid >> 6] = ls;
  __syncthreads();
  if (tid == 0) Lsh = red[0] + red[1] + red[2] + red[3];
  __syncthreads();
  float Linv = 1.0f / Lsh;
  attn_out[(size_t)b*S_ + tid]       = w0 * Linv;
  attn_out[(size_t)b*S_ + 256 + tid] = w1 * Linv;
  if (tid < 32) scs[tid] = expf(mw[b*32 + tid] - M) * Linv;
  __syncthreads();
#pragma unroll
  for (int it = 0; it < 4; ++it){
    int d = it*256 + tid;
    float acc = 0.f;
#pragma unroll
    for (int j = 0; j < 32; ++j) acc = fmaf(scs[j], ctxp[(size_t)(b*32 + j)*H_ + d], acc);
    ctx[(size_t)b*H_ + d] = acc;
  }
}

// ======================================================================
extern "C" void kernel_launch(void* const* d_in, const int* in_sizes, int n_in,
                              void* d_out, int out_size, void* d_ws, size_t ws_size,
                              hipStream_t stream){
  (void)in_sizes; (void)n_in; (void)out_size; (void)ws_size;
  const float* input_seq = (const float*)d_in[0];
  const float* last_hid  = (const float*)d_in[1];
  const float* enc       = (const float*)d_in[2];
  const float* W_ih      = (const float*)d_in[3];
  const float* b_ih      = (const float*)d_in[4];
  const float* W_hh      = (const float*)d_in[5];
  const float* b_hh      = (const float*)d_in[6];
  const float* W_attn    = (const float*)d_in[7];
  const float* b_attn    = (const float*)d_in[8];
  const float* W_concat  = (const float*)d_in[9];
  const float* b_concat  = (const float*)d_in[10];
  const float* W_out     = (const float*)d_in[11];
  const float* b_out     = (const float*)d_in[12];

  float* out = (float*)d_out;           // [0,131072) output | [131072,262144) hidden | [262144,327680) attn_w
  float* ws  = (float*)d_ws;

  // ws layout (floats), all 16B-aligned:
  float* G     = ws;                    // 8 x 786432 = 6291456 (K1 split-K planes)
  float* rnn   = ws + 6291456;          // 131072
  float* t     = ws + 6422528;          // 128
  float* e     = ws + 6422656;          // 65536
  float* mw    = ws + 6488192;          // 4096
  float* ctx   = ws + 6492288;          // 131072
  float* co    = ws + 6623360;          // 131072
  float* q     = ws + 6754432;          // 131072
  float* part  = ws + 6885504;          // 16 x 131072 = 2097152 (K3/K7/K8 planes, reused)
  float* ctxp  = ws + 8982656;          // 128*32*1024 = 4194304  -> total ~52.7 MB

  dim3 blk(256);
  // K1: gi|gh partials (grid-K x2, wave-K x4 -> 8 planes)
  gru_gemm<<<dim3(384,2), blk, 0, stream>>>(input_seq, last_hid, W_ih, W_hh, G);
  // K2: gates (sums 8 planes + biases) -> rnn, hidden out, t[b]
  gru_gates<<<128, dim3(1024), 0, stream>>>(G, last_hid, b_ih, b_hh, b_attn, rnn, out + 131072, t);
  // K3: q partials = rnn @ W_attn (W k-major, 16 planes) + dense combine
  gemm_partial<256, false, false><<<dim3(64,4), blk, 0, stream>>>(rnn, nullptr, W_attn, 1024, part);
  combine<0><<<512, blk, 0, stream>>>(part, nullptr, q);
  // K4: one-pass attention over enc (1024 blocks)
  attn_pass<<<dim3(128, 8), blk, 0, stream>>>(enc, q, t, e, ctxp, mw);
  // K5: softmax -> attn_weights out + ctx combine
  softmax_combine<<<128, blk, 0, stream>>>(e, mw, ctxp, out + 262144, ctx);
  // K7: concat head partials: [rnn|ctx] @ W_concat^T (16 planes), tanh in combine
  gemm_partial<512, true, true><<<dim3(64,4), blk, 0, stream>>>(rnn, ctx, W_concat, 2048, part);
  combine<1><<<512, blk, 0, stream>>>(part, b_concat, co);
  // K8: out head partials: co @ W_out^T (16 planes), sigmoid in combine
  gemm_partial<256, true, false><<<dim3(64,4), blk, 0, stream>>>(co, nullptr, W_out, 1024, part);
  combine<2><<<512, blk, 0, stream>>>(part, b_out, out);
}